// Round 20
// baseline (3450.380 us; speedup 1.0000x reference)
//
#include <hip/hip_runtime.h>
#include <hip/hip_bf16.h>
#include <math.h>

// ---------------- problem constants ----------------
#define B_   8
#define T_   12
#define N_   325
#define C_   64
#define NT   3900     // N_*T_
#define NTILE 21      // 16-row MFMA tiles covering 325 (+pad to 336)
#define NKK   11      // 32-k MFMA steps covering 325 (+pad to 352)
#define NTHIRD 109    // ceil(N_/3) for k45 NB=3 blocking
#define K2BLK 7800    // B_*C_*NT / 256 (exact)

typedef __attribute__((ext_vector_type(8))) short short8v;   // 8 x bf16 bits
typedef __attribute__((ext_vector_type(4))) float f32x4;

__device__ __forceinline__ float sigm(float x) { return 1.f / (1.f + expf(-x)); }

__device__ __forceinline__ unsigned short f2bf(float f) {   // RNE fp32->bf16
  unsigned u = __float_as_uint(f);
  u += 0x7FFF + ((u >> 16) & 1);
  return (unsigned short)(u >> 16);
}
__device__ __forceinline__ float bf2f(unsigned short h) {
  return __uint_as_float(((unsigned)h) << 16);
}

// 512-thread (8-wave) multi-value reduction; ONE barrier (caller ping-pongs redb)
__device__ __forceinline__ void redN(float* v, int nv, float (*redb)[4], int tid) {
#pragma unroll
  for (int off = 1; off < 64; off <<= 1) {
    for (int i = 0; i < nv; i++) v[i] += __shfl_xor(v[i], off, 64);
  }
  if ((tid & 63) == 0) {
    for (int i = 0; i < nv; i++) redb[tid >> 6][i] = v[i];
  }
  __syncthreads();
  for (int i = 0; i < nv; i++) {
    float s = 0.f;
#pragma unroll
    for (int w = 0; w < 8; w++) s += redb[w][i];
    v[i] = s;
  }
}

// cooperative fp32 M -> bf16 hi/lo fragment conversion (all 512 threads).
__device__ __forceinline__ void cvtB(const float* sbp, short8v* bfh0, short8v* bfl0,
                                     int ckbase, int ccc, bool cvalid, int cobase) {
  unsigned short* dh = (unsigned short*)bfh0;
  unsigned short* dl = (unsigned short*)bfl0;
#pragma unroll
  for (int kk = 0; kk < NKK; kk++) {
    int k = kk * 32 + ckbase;
    float v = (cvalid && k < N_) ? sbp[k * 12 + ccc] : 0.f;
    unsigned short h = f2bf(v);
    dh[kk * 512 + cobase] = h;
    dl[kk * 512 + cobase] = f2bf(v - bf2f(h));
  }
}

// ---------------- sentinel (ws too small diagnostic) ----------------
__global__ __launch_bounds__(256) void k_sentinel(float* out, int n) {
  int i = blockIdx.x * 256 + threadIdx.x;
  if (i < n) out[i] = 7.0f;
}

// ---------------- k012: merged front (k2 start conv | k1 embed | k0 frag) ---
__global__ __launch_bounds__(256) void k012_front(
    const float* __restrict__ src, const float* __restrict__ cw,
    const float* __restrict__ cbia, float* __restrict__ x,
    const float* __restrict__ sp, unsigned short* __restrict__ fragA,
    const int* __restrict__ TE, const float* __restrict__ SE,
    const float* __restrict__ w1, const float* __restrict__ b1,
    const float* __restrict__ w2, const float* __restrict__ b2,
    const float* __restrict__ sw1, const float* __restrict__ sb1,
    const float* __restrict__ sw2, const float* __restrict__ sb2,
    const float* __restrict__ t1w, const float* __restrict__ t1b,
    const float* __restrict__ t2w, const float* __restrict__ t2b,
    float* __restrict__ coef) {
  __shared__ float te2[8][10][12];
  __shared__ float ste[8][5][10];
  __shared__ float se1[5][10];
  __shared__ float se2[5][10];
  __shared__ float th[8][6][10];
  __shared__ int te64;
  const int tid = threadIdx.x;
  const int blk = blockIdx.x;
  if (blk < K2BLK) {
    int idx = blk * 256 + tid;
    int pos = idx % NT, r = idx / NT, c = r & 63, b = r >> 6;
    int n = pos / 12, t = pos - 12 * n;
    float s = src[(b * 12 + t) * N_ + n];
    x[idx] = s * cw[c] + cbia[c];
    return;
  } else if (blk > K2BLK) {
    int idx = (blk - K2BLK - 1) * 256 + tid;
    if (idx >= NTILE * NKK * 64) return;
    int lane = idx & 63, tk = idx >> 6;
    int row = (tk / NKK) * 16 + (lane & 15);
    int k0 = (tk % NKK) * 32 + (lane >> 4) * 8;
    size_t base = ((size_t)tk * 2) * 512 + (size_t)lane * 8;
#pragma unroll
    for (int j = 0; j < 8; j++) {
      int k = k0 + j;
      float v = (row < N_ && k < N_) ? sp[row * N_ + k] : 0.f;
      unsigned short h = f2bf(v);
      fragA[base + j] = h;
      fragA[base + 512 + j] = f2bf(v - bf2f(h));
    }
    return;
  }
  // ---- k1: embeddings + theta coefficients (block == K2BLK) ----
  if (tid == 0) {
    int nz = 0;
    for (int k2 = 0; k2 < 96; k2++) nz += (TE[2 * k2 + 1] != 0) ? 1 : 0;
    te64 = (nz == 0) ? 1 : 0;
  }
  __syncthreads();
  for (int idx = tid; idx < 960; idx += 256) {
    int t = idx % 12, o = (idx / 12) % 10, b = idx / 120;
    int q = (b * 12 + t) * 2;
    int d = (te64 ? TE[2 * q] : TE[q]) % 7;
    int h = (te64 ? TE[2 * q + 2] : TE[q + 1]) % 288;
    float v = w1[o * 295 + d] + w1[o * 295 + 7 + h] + b1[o];
    te2[b][o][t] = fmaxf(v, 0.f);
  }
  __syncthreads();
  for (int idx = tid; idx < 400; idx += 256) {
    int s = idx % 10, o = (idx / 10) % 5, b = idx / 50;
    float a = b2[o];
    for (int t = 0; t < 12; t++) a += te2[b][s][t] * w2[o * 12 + t];
    ste[b][o][s] = fmaxf(a, 0.f);
  }
  if (tid < 50) {
    int o = tid / 10, j = tid % 10;
    float a = sb1[o];
    for (int n = 0; n < N_; n++) a += sw1[o * N_ + n] * SE[n * 10 + j];
    se1[o][j] = fmaxf(a, 0.f);
  }
  __syncthreads();
  if (tid < 50) {
    int t = tid / 10, s = tid % 10;
    float a = sb2[s];
    for (int j = 0; j < 10; j++) a += sw2[s * 10 + j] * se1[t][j];
    se2[t][s] = fmaxf(a, 0.f);
  }
  __syncthreads();
  for (int idx = tid; idx < 400; idx += 256) {
    int s = idx % 10, o = (idx / 10) % 5, b = idx / 50;
    ste[b][o][s] = fmaxf(se2[o][s] + ste[b][o][s], 0.f);
  }
  __syncthreads();
  for (int l = 0; l < 2; l++) {
    for (int idx = tid; idx < 480; idx += 256) {
      int s = idx % 10, q = (idx / 10) % 6, b = idx / 60;
      float a = t1b[l * 6 + q];
      for (int t = 0; t < 5; t++) a += ste[b][t][s] * t1w[(l * 6 + q) * 5 + t];
      th[b][q][s] = a;
    }
    __syncthreads();
    for (int idx = tid; idx < 528; idx += 256) {
      int q = idx % 6, p = (idx / 6) % 11, b = idx / 66;
      float a = t2b[l * 11 + p];
      for (int s = 0; s < 10; s++) a += th[b][q][s] * t2w[(l * 11 + p) * 10 + s];
      coef[(l * 8 + b) * 66 + q * 11 + p] = fmaxf(a, 0.f);
    }
    __syncthreads();
  }
}

// ---------------- k3: fused basis recursion + x_st accumulation ----------------
// MFMA spatial matmul with sequential tile-groups (R11 fixed the 64-VGPR
// spill). Stable at ~242 us. fragA L2-stream floor ~69 us/launch; further
// gains need producer-consumer rewrite. Parked. Unchanged.
__global__ __launch_bounds__(512)
__attribute__((amdgpu_waves_per_eu(4, 4))) void k3_basis(
    const float* __restrict__ x, const unsigned short* __restrict__ fragA,
    const float* __restrict__ tp, const float* __restrict__ coef,
    float* __restrict__ xst) {
  __shared__ float sb[2][3940];        // 328 rows x 12 (rows 325..327 stay 0)
  __shared__ float rbuf[3936];         // R = Ls @ M, 328 rows x 12
  __shared__ float sred[2][8][4];
  __shared__ short8v bfh0[704];        // B-frag hi: [kk][kr][cc][j] (11*64 vec8)
  __shared__ short8v bfl0[704];        // B-frag lo
  const int tid = threadIdx.x;
  const int bc = blockIdx.x;
  const float* cf = coef + (bc >> 6) * 66;
  const float* xs = x + (size_t)bc * NT;
  float* xo = xst + (size_t)bc * NT;

  const int wv = tid >> 6, lane = tid & 63;
  const int ccol = lane & 15, krow = lane >> 4;   // MFMA col / k-group

  // conversion-pass mapping (all 512 threads; 11 elements each)
  const int cj = tid & 7, ccc = (tid >> 3) & 15, ckr = (tid >> 7) & 3;
  const int ckbase = ckr * 8 + cj;
  const bool cvalid = (ccc < 12);
  const int cobase = (ckr * 16 + ccc) * 8 + cj;

  // update-phase mapping: 246 threads, 4 rows x 4 cols each (rows 0..327)
  const bool upd = tid < 246;
  const int rq = tid / 3, tq = tid - 3 * (tid / 3);
  const int e0 = rq * 4 * 12 + tq * 4;

  // temporal layout: one row per thread (325 active)
  const bool actT = (tid < N_);
  const int rowOff = tid * 12;

  float w[11];
#pragma unroll
  for (int k = 0; k < 11; k++) w[k] = tp[k * 12 + k + 1];

  float last[12], sec[12], acc[12];
  int p = 0, m = 0, spc = 0;

  // zero sb pad rows (325..327 of both buffers)
  if (tid < 80) {
    int bsel = tid / 40, off = tid - 40 * bsel;
    sb[bsel][3900 + off] = 0.f;
  }

  // ---- m00 = unit(residual slice) (temporal layout) ----
  {
    float np = 0.f;
#pragma unroll
    for (int u = 0; u < 12; u++) last[u] = 0.f;
    if (actT) {
      const float4 a = *(const float4*)(xs + rowOff);
      const float4 b4 = *(const float4*)(xs + rowOff + 4);
      const float4 c4 = *(const float4*)(xs + rowOff + 8);
      last[0] = a.x; last[1] = a.y; last[2] = a.z; last[3] = a.w;
      last[4] = b4.x; last[5] = b4.y; last[6] = b4.z; last[7] = b4.w;
      last[8] = c4.x; last[9] = c4.y; last[10] = c4.z; last[11] = c4.w;
#pragma unroll
      for (int u = 0; u < 12; u++) np += last[u] * last[u];
    }
    p ^= 1; redN(&np, 1, sred[p], tid);
    const float inv = 1.f / fmaxf(sqrtf(np), 1e-8f);
    const float c0 = cf[m]; m++;
#pragma unroll
    for (int u = 0; u < 12; u++) {
      last[u] *= inv;
      acc[u] = c0 * last[u];
      sec[u] = 0.f;
    }
    if (actT) {
      float4 wv4;
      wv4.x = last[0]; wv4.y = last[1]; wv4.z = last[2]; wv4.w = last[3];
      *(float4*)&sb[0][rowOff] = wv4;
      wv4.x = last[4]; wv4.y = last[5]; wv4.z = last[6]; wv4.w = last[7];
      *(float4*)&sb[0][rowOff + 4] = wv4;
      wv4.x = last[8]; wv4.y = last[9]; wv4.z = last[10]; wv4.w = last[11];
      *(float4*)&sb[0][rowOff + 8] = wv4;
    }
    __syncthreads();
    // B-fragments for spatial step 1 (visibility via temporal redN barriers)
    cvtB(sb[0], bfh0, bfl0, ckbase, ccc, cvalid, cobase);
  }

  for (int i = 0; i <= 10; i++) {
    if (i > 0) {
      // ---------- spatial step: R = Ls @ sb[spc]  (MFMA bf16x3) ----------
      const int sps = 1 - spc;
      const bool hasSec = (i >= 2);
      // three tile-groups SEQUENTIALLY: one accumulator live at a time
#pragma unroll 1
      for (int g = 0; g < 3; g++) {
        const int tile = wv + g * 8;
        if (tile < NTILE) {
          f32x4 cc = {0.f, 0.f, 0.f, 0.f};
#pragma unroll 1
          for (int kk = 0; kk < NKK; kk++) {
            const short8v bh = bfh0[kk * 64 + lane];
            const short8v bl = bfl0[kk * 64 + lane];
            const short8v* pa = (const short8v*)fragA +
                                ((size_t)(tile * NKK + kk) * 2) * 64 + lane;
            short8v ah = pa[0], al = pa[64];
            cc = __builtin_amdgcn_mfma_f32_16x16x32_bf16(ah, bh, cc, 0, 0, 0);
            cc = __builtin_amdgcn_mfma_f32_16x16x32_bf16(ah, bl, cc, 0, 0, 0);
            cc = __builtin_amdgcn_mfma_f32_16x16x32_bf16(al, bh, cc, 0, 0, 0);
          }
          // writeback; C layout: col=lane&15, row=tile*16+(lane>>4)*4+reg
          if (ccol < 12) {
#pragma unroll
            for (int r = 0; r < 4; r++) {
              int row = tile * 16 + krow * 4 + r;
              if (row < 328) rbuf[row * 12 + ccol] = cc[r];  // pad rows excluded
            }
          }
        }
      }
      __syncthreads();
      // A=<r,l>, B=<r,s>, C=<l,s>, R2=<r,r> in ONE reduction
      float rt[4][4];
      float v4[4] = {0.f, 0.f, 0.f, 0.f};
      if (upd) {
#pragma unroll
        for (int ii = 0; ii < 4; ii++) {
          const float4 q = *(const float4*)&rbuf[e0 + ii * 12];
          rt[ii][0] = q.x; rt[ii][1] = q.y; rt[ii][2] = q.z; rt[ii][3] = q.w;
          const float4 lq = *(const float4*)&sb[spc][e0 + ii * 12];
          v4[0] += rt[ii][0] * lq.x + rt[ii][1] * lq.y + rt[ii][2] * lq.z + rt[ii][3] * lq.w;
          v4[3] += rt[ii][0] * rt[ii][0] + rt[ii][1] * rt[ii][1] +
                   rt[ii][2] * rt[ii][2] + rt[ii][3] * rt[ii][3];
          if (hasSec) {
            const float4 sq4 = *(const float4*)&sb[sps][e0 + ii * 12];
            v4[1] += rt[ii][0] * sq4.x + rt[ii][1] * sq4.y + rt[ii][2] * sq4.z + rt[ii][3] * sq4.w;
            v4[2] += lq.x * sq4.x + lq.y * sq4.y + lq.z * sq4.z + lq.w * sq4.w;
          }
        }
      }
      p ^= 1; redN(v4, 4, sred[p], tid);
      const float d1 = v4[0];
      const float d2 = hasSec ? (v4[1] - d1 * v4[2]) : 0.f;
      const float np = fmaxf(v4[3] - d1 * d1 - d2 * d2, 0.f);
      const float inv = 1.f / fmaxf(sqrtf(np), 1e-8f);
      const float cs = cf[m]; m++;
      if (upd) {
#pragma unroll
        for (int ii = 0; ii < 4; ii++) {
          const float4 lq = *(const float4*)&sb[spc][e0 + ii * 12];
          float sx = 0.f, sy = 0.f, sz = 0.f, sw = 0.f;
          if (hasSec) {
            const float4 sq4 = *(const float4*)&sb[sps][e0 + ii * 12];
            sx = sq4.x; sy = sq4.y; sz = sq4.z; sw = sq4.w;
          }
          float4 wv4;
          wv4.x = (rt[ii][0] - d1 * lq.x - d2 * sx) * inv;
          wv4.y = (rt[ii][1] - d1 * lq.y - d2 * sy) * inv;
          wv4.z = (rt[ii][2] - d1 * lq.z - d2 * sz) * inv;
          wv4.w = (rt[ii][3] - d1 * lq.w - d2 * sw) * inv;
          *(float4*)&sb[sps][e0 + ii * 12] = wv4;   // pad rows write 0
        }
      }
      spc = sps;
      __syncthreads();
      // B-fragments for the NEXT spatial step (skip after the last one);
      // visibility guaranteed by the temporal chain's redN barriers below.
      if (i < 10) cvtB(sb[spc], bfh0, bfl0, ckbase, ccc, cvalid, cobase);
      // temporal-layout init: load new M_i0 row; acc += c*row; sec <- 0
      if (actT) {
        const float4 a = *(const float4*)&sb[spc][rowOff];
        const float4 b4 = *(const float4*)&sb[spc][rowOff + 4];
        const float4 c4 = *(const float4*)&sb[spc][rowOff + 8];
        last[0] = a.x; last[1] = a.y; last[2] = a.z; last[3] = a.w;
        last[4] = b4.x; last[5] = b4.y; last[6] = b4.z; last[7] = b4.w;
        last[8] = c4.x; last[9] = c4.y; last[10] = c4.z; last[11] = c4.w;
#pragma unroll
        for (int u = 0; u < 12; u++) {
          acc[u] += cs * last[u];
          sec[u] = 0.f;
        }
      }
    }
    // ---------- temporal chain (5 steps); r recomputed in update pass ------
    for (int j5 = 0; j5 < 5; j5++) {
      float v4[4] = {0.f, 0.f, 0.f, 0.f};
      if (actT) {
#pragma unroll
        for (int u = 0; u < 12; u++) {
          float r = 0.f;
          if (u > 0) r += last[u - 1] * w[u - 1];
          if (u < 11) r += last[u + 1] * w[u];
          v4[0] += r * last[u];
          v4[1] += r * sec[u];
          v4[2] += last[u] * sec[u];
          v4[3] += r * r;
        }
      }
      p ^= 1; redN(v4, 4, sred[p], tid);
      const float d1 = v4[0];
      const float d2 = v4[1] - d1 * v4[2];
      const float np = fmaxf(v4[3] - d1 * d1 - d2 * d2, 0.f);
      const float inv = 1.f / fmaxf(sqrtf(np), 1e-8f);
      const float c = cf[m]; m++;
      if (actT) {
        float pm1 = 0.f;
#pragma unroll
        for (int u = 0; u < 12; u++) {
          const float tmp = last[u];
          float r = 0.f;
          if (u > 0) r += pm1 * w[u - 1];
          if (u < 11) r += last[u + 1] * w[u];
          const float v = (r - d1 * tmp - d2 * sec[u]) * inv;
          acc[u] += c * v;
          sec[u] = tmp;
          last[u] = v;
          pm1 = tmp;
        }
      }
    }
  }
  if (actT) {
    float4 wv4;
    wv4.x = acc[0]; wv4.y = acc[1]; wv4.z = acc[2]; wv4.w = acc[3];
    *(float4*)(xo + rowOff) = wv4;
    wv4.x = acc[4]; wv4.y = acc[5]; wv4.z = acc[6]; wv4.w = acc[7];
    *(float4*)(xo + rowOff + 4) = wv4;
    wv4.x = acc[8]; wv4.y = acc[9]; wv4.z = acc[10]; wv4.w = acc[11];
    *(float4*)(xo + rowOff + 8) = wv4;
  }
}

// ---------------- k45: fused layer body + (l=1) fused end MLP ---------------
// R19: 833 total; k45 ~165/launch. NEW: 512-thread blocks — each phase split
// to HALF the outputs per thread (st/pyr1/fuse: 2 not 4; pyr2/pyr3: 1 not 2).
// Per-output MAC chain and order unchanged -> bit-identical. Tests the
// per-thread-serial-path hypothesis (NB ladder + occupancy were ties).
__global__ __launch_bounds__(512) void k45_layer(
    float* __restrict__ x, const float* __restrict__ xst,
    const float* __restrict__ stw, const float* __restrict__ stb,
    const float* __restrict__ stg, const float* __restrict__ stbb,
    const float* __restrict__ stm, const float* __restrict__ stv,
    const float* __restrict__ p1w, const float* __restrict__ p1b,
    const float* __restrict__ p2w, const float* __restrict__ p2b,
    const float* __restrict__ p3w, const float* __restrict__ p3b,
    const float* __restrict__ pcw, const float* __restrict__ pcb,
    const float* __restrict__ pbg, const float* __restrict__ pbb,
    const float* __restrict__ pbm, const float* __restrict__ pbv,
    const float* __restrict__ bng, const float* __restrict__ bnb,
    const float* __restrict__ bnm, const float* __restrict__ bnv,
    const float* __restrict__ skw, const float* __restrict__ skb,
    float* __restrict__ skipb, int accum,
    const float* __restrict__ e1w, const float* __restrict__ e1b,
    const float* __restrict__ e2w, const float* __restrict__ e2b,
    float* __restrict__ out) {
  __shared__ float xr[3][64][12];
  __shared__ float xq_g1s[3][64][12];   // xq (phase<=1) aliased with g1s (>=2)
  __shared__ float hd[3][64][12];
  __shared__ float g2s[3][64][4];
  __shared__ float g3s[3][64][2];
  __shared__ float fu11[3][64];
  __shared__ float sk2[3][128];         // fused end-MLP: relu(skip) staging
  __shared__ float h2[3][256];          // fused end-MLP: hidden staging
  float (*xq)[64][12] = xq_g1s;
  float (*g1s)[64][12] = xq_g1s;
  const int tid = threadIdx.x;
  const int bid = blockIdx.x;
  const int b = bid / NTHIRD, nn = bid - NTHIRD * b;
  const int n0 = nn * 3;
  const bool val1 = (n0 + 1 < N_), val2 = (n0 + 2 < N_);
  const size_t base0 = ((size_t)b * 64) * NT + n0 * 12;
  if (tid < 192) {
    int c = tid / 3, ch = tid - 3 * (tid / 3);
    *(float4*)&xr[0][c][ch * 4] = *(const float4*)(x + base0 + (size_t)c * NT + ch * 4);
    *(float4*)&xq[0][c][ch * 4] = *(const float4*)(xst + base0 + (size_t)c * NT + ch * 4);
    float4 z = {0.f, 0.f, 0.f, 0.f};
    if (val1) {
      *(float4*)&xr[1][c][ch * 4] = *(const float4*)(x + base0 + 12 + (size_t)c * NT + ch * 4);
      *(float4*)&xq[1][c][ch * 4] = *(const float4*)(xst + base0 + 12 + (size_t)c * NT + ch * 4);
    } else {
      *(float4*)&xr[1][c][ch * 4] = z;
      *(float4*)&xq[1][c][ch * 4] = z;
    }
    if (val2) {
      *(float4*)&xr[2][c][ch * 4] = *(const float4*)(x + base0 + 24 + (size_t)c * NT + ch * 4);
      *(float4*)&xq[2][c][ch * 4] = *(const float4*)(xst + base0 + 24 + (size_t)c * NT + ch * 4);
    } else {
      *(float4*)&xr[2][c][ch * 4] = z;
      *(float4*)&xq[2][c][ch * 4] = z;
    }
  }
  __syncthreads();
  if (tid < 384) {   // st_mlp + bn: 2 outputs/thread
    int og = tid / 12, t = tid - 12 * (tid / 12);
    float a[3][2] = {{0.f}};
    const float* w0 = stw + (2 * og) * 128;
    for (int i = 0; i < 64; i++) {
      float wa = w0[i], wb = w0[128 + i];
#pragma unroll
      for (int s = 0; s < 3; s++) {
        float h = xr[s][i][t];
        a[s][0] += h * wa; a[s][1] += h * wb;
      }
    }
    for (int i = 0; i < 64; i++) {
      float wa = w0[64 + i], wb = w0[128 + 64 + i];
#pragma unroll
      for (int s = 0; s < 3; s++) {
        float h = xq[s][i][t];
        a[s][0] += h * wa; a[s][1] += h * wb;
      }
    }
#pragma unroll
    for (int k = 0; k < 2; k++) {
      int o = 2 * og + k;
      float sc = stg[o] / sqrtf(stv[o] + 1e-5f);
#pragma unroll
      for (int s = 0; s < 3; s++)
        hd[s][o][t] = (a[s][k] + stb[o] - stm[o]) * sc + stbb[o];
    }
  }
  __syncthreads();   // xq dead from here; its memory becomes g1s
  if (tid < 384) {   // pyr1 gated: 2 outputs/thread
    int og = tid / 12, t = tid - 12 * (tid / 12);
    float sa[3][2] = {{0.f}}, ua[3][2] = {{0.f}};
    const float* wsr = p1w + (2 * og) * 64;
    for (int i = 0; i < 64; i++) {
      float wa = wsr[i], wb = wsr[64 + i];
      float va = wsr[4096 + i], vb = wsr[4096 + 64 + i];
#pragma unroll
      for (int s = 0; s < 3; s++) {
        float h = hd[s][i][t];
        sa[s][0] += h * wa; sa[s][1] += h * wb;
        ua[s][0] += h * va; ua[s][1] += h * vb;
      }
    }
#pragma unroll
    for (int k = 0; k < 2; k++) {
      int o = 2 * og + k;
#pragma unroll
      for (int s = 0; s < 3; s++)
        g1s[s][o][t] = sigm(sa[s][k] + p1b[o]) * tanhf(ua[s][k] + p1b[o + 64]);
    }
  }
  if (tid < 256) {   // pyr2 gated: 1 output/thread
    int o = tid / 4, q = tid & 3;
    float sa[3] = {0.f, 0.f, 0.f}, ua[3] = {0.f, 0.f, 0.f};
    const float* wsr = p2w + o * 192;
    for (int i = 0; i < 64; i++)
#pragma unroll
      for (int kk = 0; kk < 3; kk++) {
        float wa = wsr[i * 3 + kk];
        float va = wsr[12288 + i * 3 + kk];
#pragma unroll
        for (int s = 0; s < 3; s++) {
          float h = hd[s][i][3 * q + kk];
          sa[s] += h * wa;
          ua[s] += h * va;
        }
      }
#pragma unroll
    for (int s = 0; s < 3; s++)
      g2s[s][o][q] = sigm(sa[s] + p2b[o]) * tanhf(ua[s] + p2b[o + 64]);
  } else if (tid < 384) {   // pyr3 gated: 1 output/thread
    int r = tid - 256;
    int o = r / 2, q = r & 1;
    float sa[3] = {0.f, 0.f, 0.f}, ua[3] = {0.f, 0.f, 0.f};
    const float* wsr = p3w + o * 384;
    for (int i = 0; i < 64; i++)
#pragma unroll
      for (int kk = 0; kk < 6; kk++) {
        float wa = wsr[i * 6 + kk];
        float va = wsr[24576 + i * 6 + kk];
#pragma unroll
        for (int s = 0; s < 3; s++) {
          float h = hd[s][i][6 * q + kk];
          sa[s] += h * wa;
          ua[s] += h * va;
        }
      }
#pragma unroll
    for (int s = 0; s < 3; s++)
      g3s[s][o][q] = sigm(sa[s] + p3b[o]) * tanhf(ua[s] + p3b[o + 64]);
  }
  __syncthreads();
  if (tid < 384) {   // pyramid fuse conv + bns: 2 outputs/thread
    int og = tid / 12, t = tid - 12 * (tid / 12);
    float a[3][2] = {{0.f}};
    const float* w0 = pcw + (2 * og) * 192;
    for (int c = 0; c < 64; c++) {
      float wa = w0[c], wb = w0[192 + c];
#pragma unroll
      for (int s = 0; s < 3; s++) {
        float v = g1s[s][c][t];
        a[s][0] += v * wa; a[s][1] += v * wb;
      }
    }
    float c4 = fminf(fmaxf((t - 1) * (1.f / 3.f), 0.f), 3.f);
    int q0 = (int)c4;
    float f4 = c4 - (float)q0;
    int q1 = min(q0 + 1, 3);
    for (int c = 0; c < 64; c++) {
      float wa = w0[64 + c], wb = w0[192 + 64 + c];
#pragma unroll
      for (int s = 0; s < 3; s++) {
        float v = (1.f - f4) * g2s[s][c][q0] + f4 * g2s[s][c][q1];
        a[s][0] += v * wa; a[s][1] += v * wb;
      }
    }
    float f2 = fminf(fmaxf((2 * t - 5) * (1.f / 12.f), 0.f), 1.f);
    for (int c = 0; c < 64; c++) {
      float wa = w0[128 + c], wb = w0[192 + 128 + c];
#pragma unroll
      for (int s = 0; s < 3; s++) {
        float v = (1.f - f2) * g3s[s][c][0] + f2 * g3s[s][c][1];
        a[s][0] += v * wa; a[s][1] += v * wb;
      }
    }
#pragma unroll
    for (int k = 0; k < 2; k++) {
      int o = 2 * og + k;
      float s1 = pbg[o] / sqrtf(pbv[o] + 1e-5f);
      float s2 = bng[o] / sqrtf(bnv[o] + 1e-5f);
#pragma unroll
      for (int s = 0; s < 3; s++) {
        float fv = (a[s][k] + pcb[o] - pbm[o]) * s1 + pbb[o];
        if (t == 11) fu11[s][o] = fv;
        xr[s][o][t] = (fv + xr[s][o][t] - bnm[o]) * s2 + bnb[o];
      }
    }
  }
  __syncthreads();
  if (tid < 192) {
    int c = tid / 3, ch = tid - 3 * (tid / 3);
    *(float4*)(x + base0 + (size_t)c * NT + ch * 4) = *(float4*)&xr[0][c][ch * 4];
    if (val1)
      *(float4*)(x + base0 + 12 + (size_t)c * NT + ch * 4) = *(float4*)&xr[1][c][ch * 4];
    if (val2)
      *(float4*)(x + base0 + 24 + (size_t)c * NT + ch * 4) = *(float4*)&xr[2][c][ch * 4];
  }
  if (tid < 128) {   // skip conv (t = 11 only)
    float a[3];
    a[0] = skb[tid]; a[1] = skb[tid]; a[2] = skb[tid];
    const float* wr = skw + tid * 64;
    for (int c = 0; c < 64; c++) {
      float wv = wr[c];
#pragma unroll
      for (int s = 0; s < 3; s++) a[s] += fu11[s][c] * wv;
    }
    size_t o0 = ((size_t)b * 128 + tid) * N_ + n0;
    if (accum) {
      // final layer: accumulate, ReLU, stage for fused end MLP (no store)
      sk2[0][tid] = fmaxf(skipb[o0] + a[0], 0.f);
      sk2[1][tid] = val1 ? fmaxf(skipb[o0 + 1] + a[1], 0.f) : 0.f;
      sk2[2][tid] = val2 ? fmaxf(skipb[o0 + 2] + a[2], 0.f) : 0.f;
    } else {
      skipb[o0] = a[0];
      if (val1) skipb[o0 + 1] = a[1];
      if (val2) skipb[o0 + 2] = a[2];
    }
  }
  if (accum) {   // ---- fused end MLP (former k6), identical MAC order ----
    __syncthreads();
    if (tid < 256) {
      float a1[3];
      a1[0] = e1b[tid]; a1[1] = a1[0]; a1[2] = a1[0];
      const float* wr1 = e1w + tid * 128;
      for (int ss = 0; ss < 128; ss++) {
        float wv = wr1[ss];
#pragma unroll
        for (int s = 0; s < 3; s++) a1[s] += wv * sk2[s][ss];
      }
#pragma unroll
      for (int s = 0; s < 3; s++) h2[s][tid] = fmaxf(a1[s], 0.f);
    }
    __syncthreads();
    if (tid < 36) {
      int s = tid / 12, tt = tid - 12 * (tid / 12);
      bool ok = (s == 0) || (s == 1 && val1) || (s == 2 && val2);
      if (ok) {
        float a2 = e2b[tt];
        const float* wr2 = e2w + tt * 256;
        for (int e = 0; e < 256; e++) a2 += wr2[e] * h2[s][e];
        out[((size_t)b * 12 + tt) * N_ + n0 + s] = a2;
      }
    }
  }
}

// ---------------- host ----------------
extern "C" void kernel_launch(void* const* d_in, const int* in_sizes, int n_in,
                              void* d_out, int out_size, void* d_ws, size_t ws_size,
                              hipStream_t stream) {
  (void)in_sizes; (void)n_in;
  if (ws_size < (size_t)44 * 1024 * 1024) {
    k_sentinel<<<(out_size + 255) / 256, 256, 0, stream>>>((float*)d_out, out_size);
    return;
  }
  const float* src = (const float*)d_in[0];
  const int* TE = (const int*)d_in[1];
  const float* sp = (const float*)d_in[2];
  const float* tp = (const float*)d_in[3];
  const float* SE = (const float*)d_in[4];
  const float* tmlp1_w = (const float*)d_in[5];
  const float* tmlp1_b = (const float*)d_in[6];
  const float* tmlp2_w = (const float*)d_in[7];
  const float* tmlp2_b = (const float*)d_in[8];
  const float* smlp1_w = (const float*)d_in[9];
  const float* smlp1_b = (const float*)d_in[10];
  const float* smlp2_w = (const float*)d_in[11];
  const float* smlp2_b = (const float*)d_in[12];
  const float* start_w = (const float*)d_in[13];
  const float* start_b = (const float*)d_in[14];
  const float* th1w = (const float*)d_in[15];
  const float* th1b = (const float*)d_in[16];
  const float* th2w = (const float*)d_in[17];
  const float* th2b = (const float*)d_in[18];
  const float* stw = (const float*)d_in[19];
  const float* stb = (const float*)d_in[20];
  const float* stg = (const float*)d_in[21];
  const float* stbb = (const float*)d_in[22];
  const float* stm = (const float*)d_in[23];
  const float* stv = (const float*)d_in[24];
  const float* p1w = (const float*)d_in[25];
  const float* p1b = (const float*)d_in[26];
  const float* p2w = (const float*)d_in[27];
  const float* p2b = (const float*)d_in[28];
  const float* p3w = (const float*)d_in[29];
  const float* p3b = (const float*)d_in[30];
  const float* pcw = (const float*)d_in[31];
  const float* pcb = (const float*)d_in[32];
  const float* pbg = (const float*)d_in[33];
  const float* pbb = (const float*)d_in[34];
  const float* pbm = (const float*)d_in[35];
  const float* pbv = (const float*)d_in[36];
  const float* skw = (const float*)d_in[37];
  const float* skb = (const float*)d_in[38];
  const float* bng = (const float*)d_in[39];
  const float* bnb = (const float*)d_in[40];
  const float* bnm = (const float*)d_in[41];
  const float* bnv = (const float*)d_in[42];
  const float* e1w = (const float*)d_in[43];
  const float* e1b = (const float*)d_in[44];
  const float* e2w = (const float*)d_in[45];
  const float* e2b = (const float*)d_in[46];

  float* ws = (float*)d_ws;
  float* coef = ws + 0;              // 2*8*66
  unsigned short* fragA = (unsigned short*)(ws + 8192);  // 21*11*2*512 ushort = 462KB
  float* x    = ws + 4194304;        // [B,64,N,T]
  float* xst  = ws + 6291456;        // x_st
  float* skipb= ws + 10485760;       // [B,128,N]

  // merged front: k2 (7800 blocks) | k1 (1 block) | k0 (58 blocks)
  const int k0blks = (NTILE * NKK * 64 + 255) / 256;
  k012_front<<<K2BLK + 1 + k0blks, 256, 0, stream>>>(
      src, start_w, start_b, x, sp, fragA,
      TE, SE, tmlp1_w, tmlp1_b, tmlp2_w, tmlp2_b,
      smlp1_w, smlp1_b, smlp2_w, smlp2_b,
      th1w, th1b, th2w, th2b, coef);

  for (int l = 0; l < 2; l++) {
    k3_basis<<<512, 512, 0, stream>>>(x, fragA, tp, coef + l * 528, xst);
    k45_layer<<<B_ * NTHIRD, 512, 0, stream>>>(
        x, xst,
        stw + l * 8192, stb + l * 64, stg + l * 64, stbb + l * 64,
        stm + l * 64, stv + l * 64,
        p1w + l * 8192, p1b + l * 128,
        p2w + l * 24576, p2b + l * 128,
        p3w + l * 49152, p3b + l * 128,
        pcw + l * 12288, pcb + l * 64,
        pbg + l * 64, pbb + l * 64, pbm + l * 64, pbv + l * 64,
        bng + l * 64, bnb + l * 64, bnm + l * 64, bnv + l * 64,
        skw + l * 8192, skb + l * 128,
        skipb, l,
        e1w, e1b, e2w, e2b, (float*)d_out);
  }
}

// Round 21
// 829.901 us; speedup vs baseline: 4.1576x; 4.1576x over previous
//
#include <hip/hip_runtime.h>
#include <hip/hip_bf16.h>
#include <math.h>

// ---------------- problem constants ----------------
#define B_   8
#define T_   12
#define N_   325
#define C_   64
#define NT   3900     // N_*T_
#define NTILE 21      // 16-row MFMA tiles covering 325 (+pad to 336)
#define NKK   11      // 32-k MFMA steps covering 325 (+pad to 352)
#define NTHIRD 109    // ceil(N_/3) for k45 NB=3 blocking
#define K2BLK 7800    // B_*C_*NT / 256 (exact)

typedef __attribute__((ext_vector_type(8))) short short8v;   // 8 x bf16 bits
typedef __attribute__((ext_vector_type(4))) float f32x4;

__device__ __forceinline__ float sigm(float x) { return 1.f / (1.f + expf(-x)); }

__device__ __forceinline__ unsigned short f2bf(float f) {   // RNE fp32->bf16
  unsigned u = __float_as_uint(f);
  u += 0x7FFF + ((u >> 16) & 1);
  return (unsigned short)(u >> 16);
}
__device__ __forceinline__ float bf2f(unsigned short h) {
  return __uint_as_float(((unsigned)h) << 16);
}

// 512-thread (8-wave) multi-value reduction; ONE barrier (caller ping-pongs redb)
__device__ __forceinline__ void redN(float* v, int nv, float (*redb)[4], int tid) {
#pragma unroll
  for (int off = 1; off < 64; off <<= 1) {
    for (int i = 0; i < nv; i++) v[i] += __shfl_xor(v[i], off, 64);
  }
  if ((tid & 63) == 0) {
    for (int i = 0; i < nv; i++) redb[tid >> 6][i] = v[i];
  }
  __syncthreads();
  for (int i = 0; i < nv; i++) {
    float s = 0.f;
#pragma unroll
    for (int w = 0; w < 8; w++) s += redb[w][i];
    v[i] = s;
  }
}

// cooperative fp32 M -> bf16 hi/lo fragment conversion (all 512 threads).
__device__ __forceinline__ void cvtB(const float* sbp, short8v* bfh0, short8v* bfl0,
                                     int ckbase, int ccc, bool cvalid, int cobase) {
  unsigned short* dh = (unsigned short*)bfh0;
  unsigned short* dl = (unsigned short*)bfl0;
#pragma unroll
  for (int kk = 0; kk < NKK; kk++) {
    int k = kk * 32 + ckbase;
    float v = (cvalid && k < N_) ? sbp[k * 12 + ccc] : 0.f;
    unsigned short h = f2bf(v);
    dh[kk * 512 + cobase] = h;
    dl[kk * 512 + cobase] = f2bf(v - bf2f(h));
  }
}

// ---------------- sentinel (ws too small diagnostic) ----------------
__global__ __launch_bounds__(256) void k_sentinel(float* out, int n) {
  int i = blockIdx.x * 256 + threadIdx.x;
  if (i < n) out[i] = 7.0f;
}

// ---------------- k012: merged front (k2 start conv | k1 embed | k0 frag) ---
__global__ __launch_bounds__(256) void k012_front(
    const float* __restrict__ src, const float* __restrict__ cw,
    const float* __restrict__ cbia, float* __restrict__ x,
    const float* __restrict__ sp, unsigned short* __restrict__ fragA,
    const int* __restrict__ TE, const float* __restrict__ SE,
    const float* __restrict__ w1, const float* __restrict__ b1,
    const float* __restrict__ w2, const float* __restrict__ b2,
    const float* __restrict__ sw1, const float* __restrict__ sb1,
    const float* __restrict__ sw2, const float* __restrict__ sb2,
    const float* __restrict__ t1w, const float* __restrict__ t1b,
    const float* __restrict__ t2w, const float* __restrict__ t2b,
    float* __restrict__ coef) {
  __shared__ float te2[8][10][12];
  __shared__ float ste[8][5][10];
  __shared__ float se1[5][10];
  __shared__ float se2[5][10];
  __shared__ float th[8][6][10];
  __shared__ int te64;
  const int tid = threadIdx.x;
  const int blk = blockIdx.x;
  if (blk < K2BLK) {
    int idx = blk * 256 + tid;
    int pos = idx % NT, r = idx / NT, c = r & 63, b = r >> 6;
    int n = pos / 12, t = pos - 12 * n;
    float s = src[(b * 12 + t) * N_ + n];
    x[idx] = s * cw[c] + cbia[c];
    return;
  } else if (blk > K2BLK) {
    int idx = (blk - K2BLK - 1) * 256 + tid;
    if (idx >= NTILE * NKK * 64) return;
    int lane = idx & 63, tk = idx >> 6;
    int row = (tk / NKK) * 16 + (lane & 15);
    int k0 = (tk % NKK) * 32 + (lane >> 4) * 8;
    size_t base = ((size_t)tk * 2) * 512 + (size_t)lane * 8;
#pragma unroll
    for (int j = 0; j < 8; j++) {
      int k = k0 + j;
      float v = (row < N_ && k < N_) ? sp[row * N_ + k] : 0.f;
      unsigned short h = f2bf(v);
      fragA[base + j] = h;
      fragA[base + 512 + j] = f2bf(v - bf2f(h));
    }
    return;
  }
  // ---- k1: embeddings + theta coefficients (block == K2BLK) ----
  if (tid == 0) {
    int nz = 0;
    for (int k2 = 0; k2 < 96; k2++) nz += (TE[2 * k2 + 1] != 0) ? 1 : 0;
    te64 = (nz == 0) ? 1 : 0;
  }
  __syncthreads();
  for (int idx = tid; idx < 960; idx += 256) {
    int t = idx % 12, o = (idx / 12) % 10, b = idx / 120;
    int q = (b * 12 + t) * 2;
    int d = (te64 ? TE[2 * q] : TE[q]) % 7;
    int h = (te64 ? TE[2 * q + 2] : TE[q + 1]) % 288;
    float v = w1[o * 295 + d] + w1[o * 295 + 7 + h] + b1[o];
    te2[b][o][t] = fmaxf(v, 0.f);
  }
  __syncthreads();
  for (int idx = tid; idx < 400; idx += 256) {
    int s = idx % 10, o = (idx / 10) % 5, b = idx / 50;
    float a = b2[o];
    for (int t = 0; t < 12; t++) a += te2[b][s][t] * w2[o * 12 + t];
    ste[b][o][s] = fmaxf(a, 0.f);
  }
  if (tid < 50) {
    int o = tid / 10, j = tid % 10;
    float a = sb1[o];
    for (int n = 0; n < N_; n++) a += sw1[o * N_ + n] * SE[n * 10 + j];
    se1[o][j] = fmaxf(a, 0.f);
  }
  __syncthreads();
  if (tid < 50) {
    int t = tid / 10, s = tid % 10;
    float a = sb2[s];
    for (int j = 0; j < 10; j++) a += sw2[s * 10 + j] * se1[t][j];
    se2[t][s] = fmaxf(a, 0.f);
  }
  __syncthreads();
  for (int idx = tid; idx < 400; idx += 256) {
    int s = idx % 10, o = (idx / 10) % 5, b = idx / 50;
    ste[b][o][s] = fmaxf(se2[o][s] + ste[b][o][s], 0.f);
  }
  __syncthreads();
  for (int l = 0; l < 2; l++) {
    for (int idx = tid; idx < 480; idx += 256) {
      int s = idx % 10, q = (idx / 10) % 6, b = idx / 60;
      float a = t1b[l * 6 + q];
      for (int t = 0; t < 5; t++) a += ste[b][t][s] * t1w[(l * 6 + q) * 5 + t];
      th[b][q][s] = a;
    }
    __syncthreads();
    for (int idx = tid; idx < 528; idx += 256) {
      int q = idx % 6, p = (idx / 6) % 11, b = idx / 66;
      float a = t2b[l * 11 + p];
      for (int s = 0; s < 10; s++) a += th[b][q][s] * t2w[(l * 11 + p) * 10 + s];
      coef[(l * 8 + b) * 66 + q * 11 + p] = fmaxf(a, 0.f);
    }
    __syncthreads();
  }
}

// ---------------- k3: fused basis recursion + x_st accumulation ----------------
// MFMA spatial matmul with sequential tile-groups (R11 fixed the 64-VGPR
// spill). Stable at ~242 us. Parked. Unchanged.
__global__ __launch_bounds__(512)
__attribute__((amdgpu_waves_per_eu(4, 4))) void k3_basis(
    const float* __restrict__ x, const unsigned short* __restrict__ fragA,
    const float* __restrict__ tp, const float* __restrict__ coef,
    float* __restrict__ xst) {
  __shared__ float sb[2][3940];        // 328 rows x 12 (rows 325..327 stay 0)
  __shared__ float rbuf[3936];         // R = Ls @ M, 328 rows x 12
  __shared__ float sred[2][8][4];
  __shared__ short8v bfh0[704];        // B-frag hi: [kk][kr][cc][j] (11*64 vec8)
  __shared__ short8v bfl0[704];        // B-frag lo
  const int tid = threadIdx.x;
  const int bc = blockIdx.x;
  const float* cf = coef + (bc >> 6) * 66;
  const float* xs = x + (size_t)bc * NT;
  float* xo = xst + (size_t)bc * NT;

  const int wv = tid >> 6, lane = tid & 63;
  const int ccol = lane & 15, krow = lane >> 4;   // MFMA col / k-group

  // conversion-pass mapping (all 512 threads; 11 elements each)
  const int cj = tid & 7, ccc = (tid >> 3) & 15, ckr = (tid >> 7) & 3;
  const int ckbase = ckr * 8 + cj;
  const bool cvalid = (ccc < 12);
  const int cobase = (ckr * 16 + ccc) * 8 + cj;

  // update-phase mapping: 246 threads, 4 rows x 4 cols each (rows 0..327)
  const bool upd = tid < 246;
  const int rq = tid / 3, tq = tid - 3 * (tid / 3);
  const int e0 = rq * 4 * 12 + tq * 4;

  // temporal layout: one row per thread (325 active)
  const bool actT = (tid < N_);
  const int rowOff = tid * 12;

  float w[11];
#pragma unroll
  for (int k = 0; k < 11; k++) w[k] = tp[k * 12 + k + 1];

  float last[12], sec[12], acc[12];
  int p = 0, m = 0, spc = 0;

  // zero sb pad rows (325..327 of both buffers)
  if (tid < 80) {
    int bsel = tid / 40, off = tid - 40 * bsel;
    sb[bsel][3900 + off] = 0.f;
  }

  // ---- m00 = unit(residual slice) (temporal layout) ----
  {
    float np = 0.f;
#pragma unroll
    for (int u = 0; u < 12; u++) last[u] = 0.f;
    if (actT) {
      const float4 a = *(const float4*)(xs + rowOff);
      const float4 b4 = *(const float4*)(xs + rowOff + 4);
      const float4 c4 = *(const float4*)(xs + rowOff + 8);
      last[0] = a.x; last[1] = a.y; last[2] = a.z; last[3] = a.w;
      last[4] = b4.x; last[5] = b4.y; last[6] = b4.z; last[7] = b4.w;
      last[8] = c4.x; last[9] = c4.y; last[10] = c4.z; last[11] = c4.w;
#pragma unroll
      for (int u = 0; u < 12; u++) np += last[u] * last[u];
    }
    p ^= 1; redN(&np, 1, sred[p], tid);
    const float inv = 1.f / fmaxf(sqrtf(np), 1e-8f);
    const float c0 = cf[m]; m++;
#pragma unroll
    for (int u = 0; u < 12; u++) {
      last[u] *= inv;
      acc[u] = c0 * last[u];
      sec[u] = 0.f;
    }
    if (actT) {
      float4 wv4;
      wv4.x = last[0]; wv4.y = last[1]; wv4.z = last[2]; wv4.w = last[3];
      *(float4*)&sb[0][rowOff] = wv4;
      wv4.x = last[4]; wv4.y = last[5]; wv4.z = last[6]; wv4.w = last[7];
      *(float4*)&sb[0][rowOff + 4] = wv4;
      wv4.x = last[8]; wv4.y = last[9]; wv4.z = last[10]; wv4.w = last[11];
      *(float4*)&sb[0][rowOff + 8] = wv4;
    }
    __syncthreads();
    // B-fragments for spatial step 1 (visibility via temporal redN barriers)
    cvtB(sb[0], bfh0, bfl0, ckbase, ccc, cvalid, cobase);
  }

  for (int i = 0; i <= 10; i++) {
    if (i > 0) {
      // ---------- spatial step: R = Ls @ sb[spc]  (MFMA bf16x3) ----------
      const int sps = 1 - spc;
      const bool hasSec = (i >= 2);
      // three tile-groups SEQUENTIALLY: one accumulator live at a time
#pragma unroll 1
      for (int g = 0; g < 3; g++) {
        const int tile = wv + g * 8;
        if (tile < NTILE) {
          f32x4 cc = {0.f, 0.f, 0.f, 0.f};
#pragma unroll 1
          for (int kk = 0; kk < NKK; kk++) {
            const short8v bh = bfh0[kk * 64 + lane];
            const short8v bl = bfl0[kk * 64 + lane];
            const short8v* pa = (const short8v*)fragA +
                                ((size_t)(tile * NKK + kk) * 2) * 64 + lane;
            short8v ah = pa[0], al = pa[64];
            cc = __builtin_amdgcn_mfma_f32_16x16x32_bf16(ah, bh, cc, 0, 0, 0);
            cc = __builtin_amdgcn_mfma_f32_16x16x32_bf16(ah, bl, cc, 0, 0, 0);
            cc = __builtin_amdgcn_mfma_f32_16x16x32_bf16(al, bh, cc, 0, 0, 0);
          }
          // writeback; C layout: col=lane&15, row=tile*16+(lane>>4)*4+reg
          if (ccol < 12) {
#pragma unroll
            for (int r = 0; r < 4; r++) {
              int row = tile * 16 + krow * 4 + r;
              if (row < 328) rbuf[row * 12 + ccol] = cc[r];  // pad rows excluded
            }
          }
        }
      }
      __syncthreads();
      // A=<r,l>, B=<r,s>, C=<l,s>, R2=<r,r> in ONE reduction
      float rt[4][4];
      float v4[4] = {0.f, 0.f, 0.f, 0.f};
      if (upd) {
#pragma unroll
        for (int ii = 0; ii < 4; ii++) {
          const float4 q = *(const float4*)&rbuf[e0 + ii * 12];
          rt[ii][0] = q.x; rt[ii][1] = q.y; rt[ii][2] = q.z; rt[ii][3] = q.w;
          const float4 lq = *(const float4*)&sb[spc][e0 + ii * 12];
          v4[0] += rt[ii][0] * lq.x + rt[ii][1] * lq.y + rt[ii][2] * lq.z + rt[ii][3] * lq.w;
          v4[3] += rt[ii][0] * rt[ii][0] + rt[ii][1] * rt[ii][1] +
                   rt[ii][2] * rt[ii][2] + rt[ii][3] * rt[ii][3];
          if (hasSec) {
            const float4 sq4 = *(const float4*)&sb[sps][e0 + ii * 12];
            v4[1] += rt[ii][0] * sq4.x + rt[ii][1] * sq4.y + rt[ii][2] * sq4.z + rt[ii][3] * sq4.w;
            v4[2] += lq.x * sq4.x + lq.y * sq4.y + lq.z * sq4.z + lq.w * sq4.w;
          }
        }
      }
      p ^= 1; redN(v4, 4, sred[p], tid);
      const float d1 = v4[0];
      const float d2 = hasSec ? (v4[1] - d1 * v4[2]) : 0.f;
      const float np = fmaxf(v4[3] - d1 * d1 - d2 * d2, 0.f);
      const float inv = 1.f / fmaxf(sqrtf(np), 1e-8f);
      const float cs = cf[m]; m++;
      if (upd) {
#pragma unroll
        for (int ii = 0; ii < 4; ii++) {
          const float4 lq = *(const float4*)&sb[spc][e0 + ii * 12];
          float sx = 0.f, sy = 0.f, sz = 0.f, sw = 0.f;
          if (hasSec) {
            const float4 sq4 = *(const float4*)&sb[sps][e0 + ii * 12];
            sx = sq4.x; sy = sq4.y; sz = sq4.z; sw = sq4.w;
          }
          float4 wv4;
          wv4.x = (rt[ii][0] - d1 * lq.x - d2 * sx) * inv;
          wv4.y = (rt[ii][1] - d1 * lq.y - d2 * sy) * inv;
          wv4.z = (rt[ii][2] - d1 * lq.z - d2 * sz) * inv;
          wv4.w = (rt[ii][3] - d1 * lq.w - d2 * sw) * inv;
          *(float4*)&sb[sps][e0 + ii * 12] = wv4;   // pad rows write 0
        }
      }
      spc = sps;
      __syncthreads();
      // B-fragments for the NEXT spatial step (skip after the last one);
      // visibility guaranteed by the temporal chain's redN barriers below.
      if (i < 10) cvtB(sb[spc], bfh0, bfl0, ckbase, ccc, cvalid, cobase);
      // temporal-layout init: load new M_i0 row; acc += c*row; sec <- 0
      if (actT) {
        const float4 a = *(const float4*)&sb[spc][rowOff];
        const float4 b4 = *(const float4*)&sb[spc][rowOff + 4];
        const float4 c4 = *(const float4*)&sb[spc][rowOff + 8];
        last[0] = a.x; last[1] = a.y; last[2] = a.z; last[3] = a.w;
        last[4] = b4.x; last[5] = b4.y; last[6] = b4.z; last[7] = b4.w;
        last[8] = c4.x; last[9] = c4.y; last[10] = c4.z; last[11] = c4.w;
#pragma unroll
        for (int u = 0; u < 12; u++) {
          acc[u] += cs * last[u];
          sec[u] = 0.f;
        }
      }
    }
    // ---------- temporal chain (5 steps); r recomputed in update pass ------
    for (int j5 = 0; j5 < 5; j5++) {
      float v4[4] = {0.f, 0.f, 0.f, 0.f};
      if (actT) {
#pragma unroll
        for (int u = 0; u < 12; u++) {
          float r = 0.f;
          if (u > 0) r += last[u - 1] * w[u - 1];
          if (u < 11) r += last[u + 1] * w[u];
          v4[0] += r * last[u];
          v4[1] += r * sec[u];
          v4[2] += last[u] * sec[u];
          v4[3] += r * r;
        }
      }
      p ^= 1; redN(v4, 4, sred[p], tid);
      const float d1 = v4[0];
      const float d2 = v4[1] - d1 * v4[2];
      const float np = fmaxf(v4[3] - d1 * d1 - d2 * d2, 0.f);
      const float inv = 1.f / fmaxf(sqrtf(np), 1e-8f);
      const float c = cf[m]; m++;
      if (actT) {
        float pm1 = 0.f;
#pragma unroll
        for (int u = 0; u < 12; u++) {
          const float tmp = last[u];
          float r = 0.f;
          if (u > 0) r += pm1 * w[u - 1];
          if (u < 11) r += last[u + 1] * w[u];
          const float v = (r - d1 * tmp - d2 * sec[u]) * inv;
          acc[u] += c * v;
          sec[u] = tmp;
          last[u] = v;
          pm1 = tmp;
        }
      }
    }
  }
  if (actT) {
    float4 wv4;
    wv4.x = acc[0]; wv4.y = acc[1]; wv4.z = acc[2]; wv4.w = acc[3];
    *(float4*)(xo + rowOff) = wv4;
    wv4.x = acc[4]; wv4.y = acc[5]; wv4.z = acc[6]; wv4.w = acc[7];
    *(float4*)(xo + rowOff + 4) = wv4;
    wv4.x = acc[8]; wv4.y = acc[9]; wv4.z = acc[10]; wv4.w = acc[11];
    *(float4*)(xo + rowOff + 8) = wv4;
  }
}

// ---------------- k45: fused layer body + (l=1) fused end MLP ---------------
// REVERTED to R19's exact 256-thread form (833 us total, session best).
// R20's 512-thread split spilled catastrophically (VGPR 128, WRITE 1.35 GB,
// k45 1430 us): on this allocator the 256-thread multi-phase shape is
// load-bearing. Do not change thread count here.
__global__ __launch_bounds__(256) void k45_layer(
    float* __restrict__ x, const float* __restrict__ xst,
    const float* __restrict__ stw, const float* __restrict__ stb,
    const float* __restrict__ stg, const float* __restrict__ stbb,
    const float* __restrict__ stm, const float* __restrict__ stv,
    const float* __restrict__ p1w, const float* __restrict__ p1b,
    const float* __restrict__ p2w, const float* __restrict__ p2b,
    const float* __restrict__ p3w, const float* __restrict__ p3b,
    const float* __restrict__ pcw, const float* __restrict__ pcb,
    const float* __restrict__ pbg, const float* __restrict__ pbb,
    const float* __restrict__ pbm, const float* __restrict__ pbv,
    const float* __restrict__ bng, const float* __restrict__ bnb,
    const float* __restrict__ bnm, const float* __restrict__ bnv,
    const float* __restrict__ skw, const float* __restrict__ skb,
    float* __restrict__ skipb, int accum,
    const float* __restrict__ e1w, const float* __restrict__ e1b,
    const float* __restrict__ e2w, const float* __restrict__ e2b,
    float* __restrict__ out) {
  __shared__ float xr[3][64][12];
  __shared__ float xq_g1s[3][64][12];   // xq (phase<=1) aliased with g1s (>=2)
  __shared__ float hd[3][64][12];
  __shared__ float g2s[3][64][4];
  __shared__ float g3s[3][64][2];
  __shared__ float fu11[3][64];
  __shared__ float sk2[3][128];         // fused end-MLP: relu(skip) staging
  __shared__ float h2[3][256];          // fused end-MLP: hidden staging
  float (*xq)[64][12] = xq_g1s;
  float (*g1s)[64][12] = xq_g1s;
  const int tid = threadIdx.x;
  const int bid = blockIdx.x;
  const int b = bid / NTHIRD, nn = bid - NTHIRD * b;
  const int n0 = nn * 3;
  const bool val1 = (n0 + 1 < N_), val2 = (n0 + 2 < N_);
  const size_t base0 = ((size_t)b * 64) * NT + n0 * 12;
  if (tid < 192) {
    int c = tid / 3, ch = tid - 3 * (tid / 3);
    *(float4*)&xr[0][c][ch * 4] = *(const float4*)(x + base0 + (size_t)c * NT + ch * 4);
    *(float4*)&xq[0][c][ch * 4] = *(const float4*)(xst + base0 + (size_t)c * NT + ch * 4);
    float4 z = {0.f, 0.f, 0.f, 0.f};
    if (val1) {
      *(float4*)&xr[1][c][ch * 4] = *(const float4*)(x + base0 + 12 + (size_t)c * NT + ch * 4);
      *(float4*)&xq[1][c][ch * 4] = *(const float4*)(xst + base0 + 12 + (size_t)c * NT + ch * 4);
    } else {
      *(float4*)&xr[1][c][ch * 4] = z;
      *(float4*)&xq[1][c][ch * 4] = z;
    }
    if (val2) {
      *(float4*)&xr[2][c][ch * 4] = *(const float4*)(x + base0 + 24 + (size_t)c * NT + ch * 4);
      *(float4*)&xq[2][c][ch * 4] = *(const float4*)(xst + base0 + 24 + (size_t)c * NT + ch * 4);
    } else {
      *(float4*)&xr[2][c][ch * 4] = z;
      *(float4*)&xq[2][c][ch * 4] = z;
    }
  }
  __syncthreads();
  if (tid < 192) {   // st_mlp + bn
    int oq = tid / 12, t = tid - 12 * (tid / 12);
    float a[3][4] = {{0.f}};
    const float* w0 = stw + (4 * oq) * 128;
    for (int i = 0; i < 64; i++) {
      float wa = w0[i], wb = w0[128 + i], wc = w0[256 + i], wd = w0[384 + i];
#pragma unroll
      for (int s = 0; s < 3; s++) {
        float h = xr[s][i][t];
        a[s][0] += h * wa; a[s][1] += h * wb; a[s][2] += h * wc; a[s][3] += h * wd;
      }
    }
    for (int i = 0; i < 64; i++) {
      float wa = w0[64 + i], wb = w0[192 + i], wc = w0[320 + i], wd = w0[448 + i];
#pragma unroll
      for (int s = 0; s < 3; s++) {
        float h = xq[s][i][t];
        a[s][0] += h * wa; a[s][1] += h * wb; a[s][2] += h * wc; a[s][3] += h * wd;
      }
    }
#pragma unroll
    for (int k = 0; k < 4; k++) {
      int o = 4 * oq + k;
      float sc = stg[o] / sqrtf(stv[o] + 1e-5f);
#pragma unroll
      for (int s = 0; s < 3; s++)
        hd[s][o][t] = (a[s][k] + stb[o] - stm[o]) * sc + stbb[o];
    }
  }
  __syncthreads();   // xq dead from here; its memory becomes g1s
  if (tid < 192) {   // pyr1 gated
    int oq = tid / 12, t = tid - 12 * (tid / 12);
    float sa[3][4] = {{0.f}}, ua[3][4] = {{0.f}};
    const float* wsr = p1w + (4 * oq) * 64;
    for (int i = 0; i < 64; i++) {
      float wa = wsr[i], wb = wsr[64 + i], wc = wsr[128 + i], wd = wsr[192 + i];
      float va = wsr[4096 + i], vb = wsr[4096 + 64 + i];
      float vc = wsr[4096 + 128 + i], vd = wsr[4096 + 192 + i];
#pragma unroll
      for (int s = 0; s < 3; s++) {
        float h = hd[s][i][t];
        sa[s][0] += h * wa; sa[s][1] += h * wb; sa[s][2] += h * wc; sa[s][3] += h * wd;
        ua[s][0] += h * va; ua[s][1] += h * vb; ua[s][2] += h * vc; ua[s][3] += h * vd;
      }
    }
#pragma unroll
    for (int k = 0; k < 4; k++) {
      int o = 4 * oq + k;
#pragma unroll
      for (int s = 0; s < 3; s++)
        g1s[s][o][t] = sigm(sa[s][k] + p1b[o]) * tanhf(ua[s][k] + p1b[o + 64]);
    }
  }
  if (tid < 128) {   // pyr2 gated
    int oq = tid / 4, q = tid & 3;
    float sa[3][2] = {{0.f}}, ua[3][2] = {{0.f}};
    const float* wsr = p2w + (2 * oq) * 192;
    for (int i = 0; i < 64; i++)
#pragma unroll
      for (int kk = 0; kk < 3; kk++) {
        float wa = wsr[i * 3 + kk], wb = wsr[192 + i * 3 + kk];
        float va = wsr[12288 + i * 3 + kk], vb = wsr[12288 + 192 + i * 3 + kk];
#pragma unroll
        for (int s = 0; s < 3; s++) {
          float h = hd[s][i][3 * q + kk];
          sa[s][0] += h * wa; sa[s][1] += h * wb;
          ua[s][0] += h * va; ua[s][1] += h * vb;
        }
      }
    int o = 2 * oq;
#pragma unroll
    for (int s = 0; s < 3; s++) {
      g2s[s][o][q] = sigm(sa[s][0] + p2b[o]) * tanhf(ua[s][0] + p2b[o + 64]);
      g2s[s][o + 1][q] = sigm(sa[s][1] + p2b[o + 1]) * tanhf(ua[s][1] + p2b[o + 65]);
    }
  } else if (tid < 192) {   // pyr3 gated
    int r = tid - 128;
    int oq = r / 2, q = r & 1;
    float sa[3][2] = {{0.f}}, ua[3][2] = {{0.f}};
    const float* wsr = p3w + (2 * oq) * 384;
    for (int i = 0; i < 64; i++)
#pragma unroll
      for (int kk = 0; kk < 6; kk++) {
        float wa = wsr[i * 6 + kk], wb = wsr[384 + i * 6 + kk];
        float va = wsr[24576 + i * 6 + kk], vb = wsr[24576 + 384 + i * 6 + kk];
#pragma unroll
        for (int s = 0; s < 3; s++) {
          float h = hd[s][i][6 * q + kk];
          sa[s][0] += h * wa; sa[s][1] += h * wb;
          ua[s][0] += h * va; ua[s][1] += h * vb;
        }
      }
    int o = 2 * oq;
#pragma unroll
    for (int s = 0; s < 3; s++) {
      g3s[s][o][q] = sigm(sa[s][0] + p3b[o]) * tanhf(ua[s][0] + p3b[o + 64]);
      g3s[s][o + 1][q] = sigm(sa[s][1] + p3b[o + 1]) * tanhf(ua[s][1] + p3b[o + 65]);
    }
  }
  __syncthreads();
  if (tid < 192) {   // pyramid fuse conv + bns
    int oq = tid / 12, t = tid - 12 * (tid / 12);
    float a[3][4] = {{0.f}};
    const float* w0 = pcw + (4 * oq) * 192;
    for (int c = 0; c < 64; c++) {
      float wa = w0[c], wb = w0[192 + c], wc = w0[384 + c], wd = w0[576 + c];
#pragma unroll
      for (int s = 0; s < 3; s++) {
        float v = g1s[s][c][t];
        a[s][0] += v * wa; a[s][1] += v * wb; a[s][2] += v * wc; a[s][3] += v * wd;
      }
    }
    float c4 = fminf(fmaxf((t - 1) * (1.f / 3.f), 0.f), 3.f);
    int q0 = (int)c4;
    float f4 = c4 - (float)q0;
    int q1 = min(q0 + 1, 3);
    for (int c = 0; c < 64; c++) {
      float wa = w0[64 + c], wb = w0[192 + 64 + c], wc = w0[384 + 64 + c], wd = w0[576 + 64 + c];
#pragma unroll
      for (int s = 0; s < 3; s++) {
        float v = (1.f - f4) * g2s[s][c][q0] + f4 * g2s[s][c][q1];
        a[s][0] += v * wa; a[s][1] += v * wb; a[s][2] += v * wc; a[s][3] += v * wd;
      }
    }
    float f2 = fminf(fmaxf((2 * t - 5) * (1.f / 12.f), 0.f), 1.f);
    for (int c = 0; c < 64; c++) {
      float wa = w0[128 + c], wb = w0[192 + 128 + c], wc = w0[384 + 128 + c], wd = w0[576 + 128 + c];
#pragma unroll
      for (int s = 0; s < 3; s++) {
        float v = (1.f - f2) * g3s[s][c][0] + f2 * g3s[s][c][1];
        a[s][0] += v * wa; a[s][1] += v * wb; a[s][2] += v * wc; a[s][3] += v * wd;
      }
    }
#pragma unroll
    for (int k = 0; k < 4; k++) {
      int o = 4 * oq + k;
      float s1 = pbg[o] / sqrtf(pbv[o] + 1e-5f);
      float s2 = bng[o] / sqrtf(bnv[o] + 1e-5f);
#pragma unroll
      for (int s = 0; s < 3; s++) {
        float fv = (a[s][k] + pcb[o] - pbm[o]) * s1 + pbb[o];
        if (t == 11) fu11[s][o] = fv;
        xr[s][o][t] = (fv + xr[s][o][t] - bnm[o]) * s2 + bnb[o];
      }
    }
  }
  __syncthreads();
  if (tid < 192) {
    int c = tid / 3, ch = tid - 3 * (tid / 3);
    *(float4*)(x + base0 + (size_t)c * NT + ch * 4) = *(float4*)&xr[0][c][ch * 4];
    if (val1)
      *(float4*)(x + base0 + 12 + (size_t)c * NT + ch * 4) = *(float4*)&xr[1][c][ch * 4];
    if (val2)
      *(float4*)(x + base0 + 24 + (size_t)c * NT + ch * 4) = *(float4*)&xr[2][c][ch * 4];
  }
  if (tid < 128) {   // skip conv (t = 11 only)
    float a[3];
    a[0] = skb[tid]; a[1] = skb[tid]; a[2] = skb[tid];
    const float* wr = skw + tid * 64;
    for (int c = 0; c < 64; c++) {
      float wv = wr[c];
#pragma unroll
      for (int s = 0; s < 3; s++) a[s] += fu11[s][c] * wv;
    }
    size_t o0 = ((size_t)b * 128 + tid) * N_ + n0;
    if (accum) {
      // final layer: accumulate, ReLU, stage for fused end MLP (no store)
      sk2[0][tid] = fmaxf(skipb[o0] + a[0], 0.f);
      sk2[1][tid] = val1 ? fmaxf(skipb[o0 + 1] + a[1], 0.f) : 0.f;
      sk2[2][tid] = val2 ? fmaxf(skipb[o0 + 2] + a[2], 0.f) : 0.f;
    } else {
      skipb[o0] = a[0];
      if (val1) skipb[o0 + 1] = a[1];
      if (val2) skipb[o0 + 2] = a[2];
    }
  }
  if (accum) {   // ---- fused end MLP (former k6), identical MAC order ----
    __syncthreads();
    {
      float a1[3];
      a1[0] = e1b[tid]; a1[1] = a1[0]; a1[2] = a1[0];
      const float* wr1 = e1w + tid * 128;
      for (int ss = 0; ss < 128; ss++) {
        float wv = wr1[ss];
#pragma unroll
        for (int s = 0; s < 3; s++) a1[s] += wv * sk2[s][ss];
      }
#pragma unroll
      for (int s = 0; s < 3; s++) h2[s][tid] = fmaxf(a1[s], 0.f);
    }
    __syncthreads();
    if (tid < 36) {
      int s = tid / 12, tt = tid - 12 * (tid / 12);
      bool ok = (s == 0) || (s == 1 && val1) || (s == 2 && val2);
      if (ok) {
        float a2 = e2b[tt];
        const float* wr2 = e2w + tt * 256;
        for (int e = 0; e < 256; e++) a2 += wr2[e] * h2[s][e];
        out[((size_t)b * 12 + tt) * N_ + n0 + s] = a2;
      }
    }
  }
}

// ---------------- host ----------------
extern "C" void kernel_launch(void* const* d_in, const int* in_sizes, int n_in,
                              void* d_out, int out_size, void* d_ws, size_t ws_size,
                              hipStream_t stream) {
  (void)in_sizes; (void)n_in;
  if (ws_size < (size_t)44 * 1024 * 1024) {
    k_sentinel<<<(out_size + 255) / 256, 256, 0, stream>>>((float*)d_out, out_size);
    return;
  }
  const float* src = (const float*)d_in[0];
  const int* TE = (const int*)d_in[1];
  const float* sp = (const float*)d_in[2];
  const float* tp = (const float*)d_in[3];
  const float* SE = (const float*)d_in[4];
  const float* tmlp1_w = (const float*)d_in[5];
  const float* tmlp1_b = (const float*)d_in[6];
  const float* tmlp2_w = (const float*)d_in[7];
  const float* tmlp2_b = (const float*)d_in[8];
  const float* smlp1_w = (const float*)d_in[9];
  const float* smlp1_b = (const float*)d_in[10];
  const float* smlp2_w = (const float*)d_in[11];
  const float* smlp2_b = (const float*)d_in[12];
  const float* start_w = (const float*)d_in[13];
  const float* start_b = (const float*)d_in[14];
  const float* th1w = (const float*)d_in[15];
  const float* th1b = (const float*)d_in[16];
  const float* th2w = (const float*)d_in[17];
  const float* th2b = (const float*)d_in[18];
  const float* stw = (const float*)d_in[19];
  const float* stb = (const float*)d_in[20];
  const float* stg = (const float*)d_in[21];
  const float* stbb = (const float*)d_in[22];
  const float* stm = (const float*)d_in[23];
  const float* stv = (const float*)d_in[24];
  const float* p1w = (const float*)d_in[25];
  const float* p1b = (const float*)d_in[26];
  const float* p2w = (const float*)d_in[27];
  const float* p2b = (const float*)d_in[28];
  const float* p3w = (const float*)d_in[29];
  const float* p3b = (const float*)d_in[30];
  const float* pcw = (const float*)d_in[31];
  const float* pcb = (const float*)d_in[32];
  const float* pbg = (const float*)d_in[33];
  const float* pbb = (const float*)d_in[34];
  const float* pbm = (const float*)d_in[35];
  const float* pbv = (const float*)d_in[36];
  const float* skw = (const float*)d_in[37];
  const float* skb = (const float*)d_in[38];
  const float* bng = (const float*)d_in[39];
  const float* bnb = (const float*)d_in[40];
  const float* bnm = (const float*)d_in[41];
  const float* bnv = (const float*)d_in[42];
  const float* e1w = (const float*)d_in[43];
  const float* e1b = (const float*)d_in[44];
  const float* e2w = (const float*)d_in[45];
  const float* e2b = (const float*)d_in[46];

  float* ws = (float*)d_ws;
  float* coef = ws + 0;              // 2*8*66
  unsigned short* fragA = (unsigned short*)(ws + 8192);  // 21*11*2*512 ushort = 462KB
  float* x    = ws + 4194304;        // [B,64,N,T]
  float* xst  = ws + 6291456;        // x_st
  float* skipb= ws + 10485760;       // [B,128,N]

  // merged front: k2 (7800 blocks) | k1 (1 block) | k0 (58 blocks)
  const int k0blks = (NTILE * NKK * 64 + 255) / 256;
  k012_front<<<K2BLK + 1 + k0blks, 256, 0, stream>>>(
      src, start_w, start_b, x, sp, fragA,
      TE, SE, tmlp1_w, tmlp1_b, tmlp2_w, tmlp2_b,
      smlp1_w, smlp1_b, smlp2_w, smlp2_b,
      th1w, th1b, th2w, th2b, coef);

  for (int l = 0; l < 2; l++) {
    k3_basis<<<512, 512, 0, stream>>>(x, fragA, tp, coef + l * 528, xst);
    k45_layer<<<B_ * NTHIRD, 256, 0, stream>>>(
        x, xst,
        stw + l * 8192, stb + l * 64, stg + l * 64, stbb + l * 64,
        stm + l * 64, stv + l * 64,
        p1w + l * 8192, p1b + l * 128,
        p2w + l * 24576, p2b + l * 128,
        p3w + l * 49152, p3b + l * 128,
        pcw + l * 12288, pcb + l * 64,
        pbg + l * 64, pbb + l * 64, pbm + l * 64, pbv + l * 64,
        bng + l * 64, bnb + l * 64, bnm + l * 64, bnv + l * 64,
        skw + l * 8192, skb + l * 128,
        skipb, l,
        e1w, e1b, e2w, e2b, (float*)d_out);
  }
}